// Round 4
// baseline (824.387 us; speedup 1.0000x reference)
//
#include <hip/hip_runtime.h>

// VQ: latent [32768,8,32] f32, codebook [128,32] f32.
// Outputs (concat in d_out, fp32):
//   policy_vq_latent [262144*32], quantized [262144*32], codebook_set [32768*128*32]
//
// FROZEN arithmetic (verified absmax=0.0 in round 2 — bit-exact vs np ref):
//   S = sum(x^2), c2 = sum(c^2): numpy pairwise-8 order for n=32
//   dot = (2x) @ cb.T: sequential-k mul+add chain, NO FMA
//   dist = fl(fl(S + c2_k) - dot_k), strict < argmin (first-index ties)
//   policy = fl(x + fl(q - x))
// fp contract(off) stops hipcc re-fusing mul+add into FMA.
//
// Round-4 changes (perf only; round-3 post-mortem):
//  - RPT=4 spilled (x2=128 VGPR + cv=32 > 128-reg occupancy step): kernel
//    224 -> 428 us. Revert to RPT=2 (~90 VGPR, launch_bounds(256,4)).
//  - Role-by-range (bid<V) serialized VQ and broadcast phases (224 ~= 101 HBM
//    + 82 LDS). Stripe roles: VQ iff bid%5==0 over 2560 blocks -> every CU
//    gets ~2 VQ + ~8 BC blocks from t=0; lcm(5,8)=40 spreads VQ over all XCDs.
//  - k-loop: j-outer / row-inner interleave keeps cv live at 4 regs while
//    preserving each row's sequential chain bit-exactly.

typedef float f32x4 __attribute__((ext_vector_type(4)));

constexpr int N_ROWS    = 32768 * 8;   // 262144 flat vectors
constexpr int KCODES    = 128;
constexpr int DIM       = 32;
constexpr int THREADS   = 256;
constexpr int RPT       = 2;                               // rows per thread
constexpr int VQ_BLOCKS = N_ROWS / (THREADS * RPT);        // 512
constexpr int TOTAL_BLOCKS = 2560;                         // 512 VQ + 2048 BC
constexpr int BC_BLOCKS = TOTAL_BLOCKS - VQ_BLOCKS;        // 2048
constexpr long long QUANT_OFF = (long long)N_ROWS * DIM;   //  8388608 floats
constexpr long long CBSET_OFF = 2LL * N_ROWS * DIM;        // 16777216 floats
constexpr int CBSET_F4 = (int)(32768LL * 128 * 32 / 4);    // 33554432 float4
constexpr int PERIOD_F4_MASK = 1023;  // 4096 floats per codebook copy = 1024 f4

__global__ __launch_bounds__(THREADS, 4)
void vq_fused_kernel(const float* __restrict__ latent,
                     const float* __restrict__ codebook,
                     float* __restrict__ out) {
#pragma clang fp contract(off)
    __shared__ float s_cb[KCODES * DIM];  // 16 KB
    __shared__ float s_c2[KCODES];

    const int tid = threadIdx.x;
    const int bid = blockIdx.x;

    if (bid % 5 == 0) {
        const int vqid = bid / 5;  // 0..511

        // ---- stage codebook to LDS (coalesced float4) ----
        {
            f32x4* s4 = (f32x4*)s_cb;
            const f32x4* g4 = (const f32x4*)codebook;
            #pragma unroll
            for (int j = 0; j < (KCODES * DIM / 4) / THREADS; ++j)  // 4 iters
                s4[tid + THREADS * j] = g4[tid + THREADS * j];
        }
        __syncthreads();

        // ---- c2[k] = sum(c_k^2) in numpy pairwise-8 order ----
        if (tid < KCODES) {
            const float* c = &s_cb[tid * DIM];
            float t[DIM];
            #pragma unroll
            for (int d = 0; d < DIM; ++d) t[d] = c[d] * c[d];
            float r[8];
            #pragma unroll
            for (int j = 0; j < 8; ++j)
                r[j] = ((t[j] + t[j + 8]) + t[j + 16]) + t[j + 24];
            s_c2[tid] = ((r[0] + r[1]) + (r[2] + r[3])) + ((r[4] + r[5]) + (r[6] + r[7]));
        }
        __syncthreads();

        // ---- per-thread rows: row0 = base+tid, row1 = base+tid+256 ----
        const int rbase = vqid * (THREADS * RPT);

        float x2[RPT][DIM];  // 2*x (exact); x recovered later as 0.5*x2 (exact)
        float S[RPT];
        #pragma unroll
        for (int rr = 0; rr < RPT; ++rr) {
            const int row = rbase + rr * THREADS + tid;
            const f32x4* x4 = (const f32x4*)latent + (size_t)row * 8;
            float t[DIM];
            #pragma unroll
            for (int j = 0; j < 8; ++j) {
                f32x4 v = x4[j];
                #pragma unroll
                for (int e = 0; e < 4; ++e) {
                    float xv = v[e];
                    t[4 * j + e]      = xv * xv;   // individually rounded square
                    x2[rr][4 * j + e] = 2.0f * xv; // exact
                }
            }
            float r[8];
            #pragma unroll
            for (int j = 0; j < 8; ++j)
                r[j] = ((t[j] + t[j + 8]) + t[j + 16]) + t[j + 24];
            S[rr] = ((r[0] + r[1]) + (r[2] + r[3])) + ((r[4] + r[5]) + (r[6] + r[7]));
        }

        float best[RPT];
        int   bestk[RPT];
        #pragma unroll
        for (int rr = 0; rr < RPT; ++rr) { best[rr] = 3.402823466e38f; bestk[rr] = 0; }

        const f32x4* c4 = (const f32x4*)s_cb;
        #pragma unroll 2
        for (int k = 0; k < KCODES; ++k) {
            const float c2k = s_c2[k];
            float acc[RPT];
            #pragma unroll
            for (int rr = 0; rr < RPT; ++rr) acc[rr] = 0.0f;
            // j-outer / row-inner: cv live = 4 regs; each row's chain stays
            // FROZEN (ascending d, single accumulator, mul then add, no FMA).
            #pragma unroll
            for (int j = 0; j < 8; ++j) {
                f32x4 cv = c4[k * 8 + j];  // uniform addr -> LDS broadcast
                #pragma unroll
                for (int rr = 0; rr < RPT; ++rr) {
                    #pragma unroll
                    for (int e = 0; e < 4; ++e) {
                        float prod = x2[rr][4 * j + e] * cv[e];  // fl(2x*c)
                        acc[rr] = acc[rr] + prod;                // fl(acc+prod)
                    }
                }
            }
            #pragma unroll
            for (int rr = 0; rr < RPT; ++rr) {
                float dist = (S[rr] + c2k) - acc[rr];  // fl(fl(S+c2) - dot2)
                if (dist < best[rr]) { best[rr] = dist; bestk[rr] = k; }  // strict <
            }
        }

        // ---- epilogue: policy = x + (q - x), quantized = q ----
        #pragma unroll
        for (int rr = 0; rr < RPT; ++rr) {
            const int row = rbase + rr * THREADS + tid;
            f32x4* pol = (f32x4*)out + (size_t)row * 8;
            f32x4* qnt = (f32x4*)(out + QUANT_OFF) + (size_t)row * 8;
            const f32x4* q4 = (const f32x4*)&s_cb[bestk[rr] * DIM];
            #pragma unroll
            for (int j = 0; j < 8; ++j) {
                f32x4 q = q4[j];
                f32x4 p;
                #pragma unroll
                for (int e = 0; e < 4; ++e) {
                    float xv = 0.5f * x2[rr][4 * j + e];  // exact recovery of x
                    p[e] = xv + (q[e] - xv);              // mirrors l + (q - l)
                }
                __builtin_nontemporal_store(p, &pol[j]);
                __builtin_nontemporal_store(q, &qnt[j]);
            }
        }
    } else {
        // ---- broadcast codebook_set: out[b,k,d] = cb[k,d], 512 MiB stream ----
        const int bcid = bid - bid / 5 - 1;                // 0..2047
        const int btid = bcid * THREADS + tid;             // 0..524287
        const int stride = BC_BLOCKS * THREADS;            // 524288 -> 64 iters
        const f32x4* g4 = (const f32x4*)codebook;
        f32x4* o4 = (f32x4*)(out + CBSET_OFF);
        for (int i = btid; i < CBSET_F4; i += stride) {
            f32x4 v = g4[i & PERIOD_F4_MASK];  // L1-resident 16 KB table
            __builtin_nontemporal_store(v, &o4[i]);
        }
    }
}

extern "C" void kernel_launch(void* const* d_in, const int* in_sizes, int n_in,
                              void* d_out, int out_size, void* d_ws, size_t ws_size,
                              hipStream_t stream) {
    const float* latent   = (const float*)d_in[0];
    const float* codebook = (const float*)d_in[1];
    float* out = (float*)d_out;
    vq_fused_kernel<<<dim3(TOTAL_BLOCKS), dim3(THREADS), 0, stream>>>(
        latent, codebook, out);
}

// Round 5
// 636.761 us; speedup vs baseline: 1.2947x; 1.2947x over previous
//
#include <hip/hip_runtime.h>

// VQ: latent [32768,8,32] f32, codebook [128,32] f32.
// Outputs (concat in d_out, fp32):
//   policy_vq_latent [262144*32], quantized [262144*32], codebook_set [32768*128*32]
//
// FROZEN arithmetic (verified absmax=0.0 in rounds 2-4 — bit-exact vs np ref):
//   S = sum(x^2), c2 = sum(c^2): numpy pairwise-8 order for n=32
//   dot = (2x) @ cb.T: sequential-k mul+add chain, NO FMA
//   dist = fl(fl(S + c2_k) - dot_k), strict < argmin (first-index ties)
//   policy = fl(x + fl(q - x))
// fp contract(off) stops hipcc re-fusing mul+add into FMA.
//
// Round-5: revert to the exact r2 structure (RPT=1, role-by-range, kernel
// ~224us; r3/r4's multi-row variants both regressed ~2x for reasons the
// counters couldn't isolate). Single change: the k-loop reads the codebook
// from GLOBAL memory at a wave-uniform address -> AMDGPU uniformity analysis
// emits s_load (scalar pipe, sL1-resident 16KB) instead of 8x ds_read_b128
// on the LDS pipe (~82us/CU in r2, the dominant VQ cost). LDS now holds only
// c2 (512B); the epilogue gathers q from the L1-resident global codebook.

typedef float f32x4 __attribute__((ext_vector_type(4)));

constexpr int N_ROWS    = 32768 * 8;   // 262144 flat vectors
constexpr int KCODES    = 128;
constexpr int DIM       = 32;
constexpr int THREADS   = 256;
constexpr int VQ_BLOCKS = N_ROWS / THREADS;  // 1024 (1 row per thread)
constexpr int BC_BLOCKS = 2048;              // broadcast blocks
constexpr long long QUANT_OFF = (long long)N_ROWS * DIM;   //  8388608 floats
constexpr long long CBSET_OFF = 2LL * N_ROWS * DIM;        // 16777216 floats
constexpr int CBSET_F4 = (int)(32768LL * 128 * 32 / 4);    // 33554432 float4
constexpr int PERIOD_F4_MASK = 1023;  // 4096 floats per codebook copy = 1024 f4

__global__ __launch_bounds__(THREADS)
void vq_fused_kernel(const float* __restrict__ latent,
                     const float* __restrict__ codebook,
                     float* __restrict__ out) {
#pragma clang fp contract(off)
    __shared__ float s_c2[KCODES];  // 512 B — the only LDS

    const int tid = threadIdx.x;
    const int bid = blockIdx.x;

    if (bid < VQ_BLOCKS) {
        // ---- c2[k] = sum(c_k^2) in numpy pairwise-8 order (global reads,
        //      16KB codebook is L1/sL1-resident after first touch) ----
        if (tid < KCODES) {
            const float* c = codebook + tid * DIM;
            float t[DIM];
            #pragma unroll
            for (int d = 0; d < DIM; ++d) { float cv = c[d]; t[d] = cv * cv; }
            float r[8];
            #pragma unroll
            for (int j = 0; j < 8; ++j)
                r[j] = ((t[j] + t[j + 8]) + t[j + 16]) + t[j + 24];
            s_c2[tid] = ((r[0] + r[1]) + (r[2] + r[3])) + ((r[4] + r[5]) + (r[6] + r[7]));
        }
        __syncthreads();

        // ---- per-row VQ (1 row per thread) ----
        const int row = bid * THREADS + tid;
        const f32x4* x4 = (const f32x4*)latent + (size_t)row * 8;

        float x2[DIM];  // 2*x (exact); x recovered later as 0.5*x2 (exact)
        float S;
        {
            float t[DIM];
            #pragma unroll
            for (int j = 0; j < 8; ++j) {
                f32x4 v = x4[j];
                #pragma unroll
                for (int e = 0; e < 4; ++e) {
                    float xv = v[e];
                    t[4 * j + e]  = xv * xv;     // individually rounded square
                    x2[4 * j + e] = 2.0f * xv;   // exact
                }
            }
            float r[8];
            #pragma unroll
            for (int j = 0; j < 8; ++j)
                r[j] = ((t[j] + t[j + 8]) + t[j + 16]) + t[j + 24];
            S = ((r[0] + r[1]) + (r[2] + r[3])) + ((r[4] + r[5]) + (r[6] + r[7]));
        }

        float best = 3.402823466e38f;
        int bestk = 0;
        const f32x4* c4 = (const f32x4*)codebook;  // GLOBAL, wave-uniform index
        #pragma unroll 4
        for (int k = 0; k < KCODES; ++k) {
            // FROZEN: sequential mul+add chain, ascending d, single acc, no FMA.
            float acc = 0.0f;
            #pragma unroll
            for (int j = 0; j < 8; ++j) {
                f32x4 cv = c4[k * 8 + j];  // uniform addr -> s_load (scalar pipe)
                #pragma unroll
                for (int e = 0; e < 4; ++e) {
                    float prod = x2[4 * j + e] * cv[e];  // fl(2x * c)
                    acc = acc + prod;                    // fl(acc + prod)
                }
            }
            float dist = (S + s_c2[k]) - acc;  // fl(fl(S+c2) - dot2)
            if (dist < best) { best = dist; bestk = k; }  // strict <: first min
        }

        // ---- epilogue: policy = x + (q - x), quantized = q ----
        f32x4* pol = (f32x4*)out + (size_t)row * 8;
        f32x4* qnt = (f32x4*)(out + QUANT_OFF) + (size_t)row * 8;
        const f32x4* q4 = (const f32x4*)(codebook + bestk * DIM);  // L1-hit gather
        #pragma unroll
        for (int j = 0; j < 8; ++j) {
            f32x4 q = q4[j];
            f32x4 p;
            #pragma unroll
            for (int e = 0; e < 4; ++e) {
                float xv = 0.5f * x2[4 * j + e];  // exact recovery of x
                p[e] = xv + (q[e] - xv);          // mirrors l + (q - l)
            }
            pol[j] = p;
            qnt[j] = q;
        }
    } else {
        // ---- broadcast codebook_set: out[b,k,d] = cb[k,d], 512 MiB stream ----
        const int btid = (bid - VQ_BLOCKS) * THREADS + tid;
        const int stride = BC_BLOCKS * THREADS;  // 524288 -> exactly 64 iters
        const f32x4* g4 = (const f32x4*)codebook;
        f32x4* o4 = (f32x4*)(out + CBSET_OFF);
        for (int i = btid; i < CBSET_F4; i += stride) {
            f32x4 v = g4[i & PERIOD_F4_MASK];  // L1-resident 16 KB table
            __builtin_nontemporal_store(v, &o4[i]);
        }
    }
}

extern "C" void kernel_launch(void* const* d_in, const int* in_sizes, int n_in,
                              void* d_out, int out_size, void* d_ws, size_t ws_size,
                              hipStream_t stream) {
    const float* latent   = (const float*)d_in[0];
    const float* codebook = (const float*)d_in[1];
    float* out = (float*)d_out;
    vq_fused_kernel<<<dim3(VQ_BLOCKS + BC_BLOCKS), dim3(THREADS), 0, stream>>>(
        latent, codebook, out);
}